// Round 1
// 211.754 us; speedup vs baseline: 1.1046x; 1.1046x over previous
//
#include <hip/hip_runtime.h>
#include <math.h>

#define Bsz 4
#define DM 96
#define DI 192
#define NS 16
#define RK 6
#define KK 4
#define HH 32
#define WW 32
#define LL 1024
#define NC 32          // chunks along L
#define CS 32          // chunk size (NC*CS == LL)

__device__ __forceinline__ float silu_f(float x) { return x / (1.f + __expf(-x)); }

// forward snake map: scan position l -> flat spatial index hw for direction k
// (inverse of the verified l_of_hw; round-trip checked for all 4 k)
__device__ __forceinline__ int hw_of_l(int k, int l) {
    int a = l >> 5, r = l & 31;
    int m = (a & 1) ? 31 - r : r;
    int h, w;
    if (k < 2) { w = a; h = m; }      // vertical snake
    else       { h = a; w = m; }      // horizontal snake
    if (k & 1) { h = 31 - h; w = 31 - w; }
    return h * 32 + w;
}

// ---- in_proj: 8 outputs per thread; also zeroes stats ---------------------
__global__ void in_proj_k(const float* __restrict__ x, const float* __restrict__ w,
                          float* __restrict__ xx, float* __restrict__ zs,
                          float* __restrict__ stats) {
    int bi = blockIdx.x;                 // 4 lblk * 48 og * 4 b
    int t = threadIdx.x;
    if (bi == 0 && t < 2 * Bsz) stats[t] = 0.f;
    int lb = bi & 3;
    int og = (bi >> 2) % 48;
    int b = bi / 192;
    int l = lb * 256 + t;
    const float* xb = x + (size_t)b * DM * LL + l;
    float acc[8];
#pragma unroll
    for (int g = 0; g < 8; g++) acc[g] = 0.f;
    for (int c = 0; c < DM; c++) {
        float xv = xb[(size_t)c * LL];
#pragma unroll
        for (int g = 0; g < 8; g++)
            acc[g] = fmaf(xv, w[(size_t)(og * 8 + g) * DM + c], acc[g]);
    }
#pragma unroll
    for (int g = 0; g < 8; g++) {
        int o = og * 8 + g;
        if (o < DI) xx[((size_t)b * DI + o) * LL + l] = acc[g];
        else        zs[((size_t)b * DI + (o - DI)) * LL + l] = silu_f(acc[g]);
    }
}

// ---- depthwise conv3x3+silu -> transposed layout xxT[b][hw][d] ------------
__global__ void convT_k(const float* __restrict__ xx, const float* __restrict__ cw,
                        const float* __restrict__ cb, float* __restrict__ xxT) {
    __shared__ float tile[32][65];
    int bi = blockIdx.x;                 // 32 rows * 3 dtiles * 4 b
    int h0 = bi % 32;
    int dt = (bi / 32) % 3;
    int b = bi / 96;
    int d0 = dt * 64;
    int t = threadIdx.x;
    int wi = t & 31, dg = t >> 5;

#pragma unroll
    for (int pass = 0; pass < 8; pass++) {
        int di = pass * 8 + dg;
        int d = d0 + di;
        const float* xp = xx + ((size_t)b * DI + d) * LL;
        const float* wp = cw + d * 9;
        float acc = cb[d];
#pragma unroll
        for (int kh = 0; kh < 3; kh++) {
            int hh = h0 + kh - 1;
            if (hh < 0 || hh >= HH) continue;
#pragma unroll
            for (int kw = 0; kw < 3; kw++) {
                int ww2 = wi + kw - 1;
                if (ww2 < 0 || ww2 >= WW) continue;
                acc = fmaf(xp[hh * WW + ww2], wp[kh * 3 + kw], acc);
            }
        }
        tile[wi][di] = silu_f(acc);
    }
    __syncthreads();

    int di = t & 63, w4 = t >> 6;
#pragma unroll
    for (int rep = 0; rep < 8; rep++) {
        int w2 = rep * 4 + w4;
        xxT[((size_t)b * LL + h0 * 32 + w2) * DI + d0 + di] = tile[w2][di];
    }
}

// ---- x_dbl: tiled GEMM; stage 64 *gathered* rows of xxT, output [bk][l][38]
__global__ void __launch_bounds__(512)
xdbl_k(const float* __restrict__ xxT, const float* __restrict__ xpw,
       float* __restrict__ xdbl) {
    __shared__ float tile[64 * 193];
    int blk = blockIdx.x;            // bk*16 + lt
    int bk = blk >> 4, lt = blk & 15;
    int k = bk & 3, b = bk >> 2;
    int t = threadIdx.x;

    const float* xb = xxT + (size_t)b * LL * DI;
#pragma unroll
    for (int i = 0; i < 6; i++) {
        int j4 = t + i * 512;
        int lr = j4 / 48;            // 48 float4 per row
        int d4 = j4 % 48;
        int hw = hw_of_l(k, lt * 64 + lr);
        float4 v = ((const float4*)(xb + (size_t)hw * DI))[d4];
        float* dst = &tile[lr * 193 + d4 * 4];
        dst[0] = v.x; dst[1] = v.y; dst[2] = v.z; dst[3] = v.w;
    }
    __syncthreads();

    int ll = t & 63;                 // lane -> l (2-way bank = free)
    int cg = t >> 6;                 // wave-uniform c-group 0..7
    int c0 = cg * 5;
    int wlim = (c0 + 5 <= 38) ? 5 : (38 - c0);   // 5,...,5,3
    const float* wk = xpw + (size_t)k * 38 * DI;

    float acc[5];
#pragma unroll
    for (int j = 0; j < 5; j++) acc[j] = 0.f;
    const float* xrow = &tile[ll * 193];
#pragma unroll 4
    for (int d = 0; d < DI; d++) {
        float xv = xrow[d];
#pragma unroll
        for (int j = 0; j < 5; j++) {
            int cc = c0 + j; cc = (cc > 37) ? 37 : cc;
            acc[j] = fmaf(xv, wk[(size_t)cc * DI + d], acc[j]);
        }
    }
    float* orow = xdbl + ((size_t)bk * LL + lt * 64 + ll) * 38;
#pragma unroll
    for (int j = 0; j < 5; j++)
        if (j < wlim) orow[c0 + j] = acc[j];
}

// ---- chunked parallel selective scan --------------------------------------
__global__ void scan_p1(const float* __restrict__ xxT, const float* __restrict__ xdbl,
                        const float* __restrict__ dtw_g, const float* __restrict__ dtb_g,
                        const float* __restrict__ Alog,
                        float* __restrict__ Pst, float* __restrict__ Hloc) {
    int blk = blockIdx.x;           // bk*NC + c
    int bk = blk / NC, c = blk % NC;
    int k = bk & 3, b = bk >> 2;
    int d = threadIdx.x;
    int kd = k * DI + d;

    float A[NS];
#pragma unroll
    for (int n = 0; n < NS; n++) A[n] = -__expf(Alog[(size_t)kd * NS + n]);
    float dtw[RK];
#pragma unroll
    for (int r = 0; r < RK; r++) dtw[r] = dtw_g[(size_t)kd * RK + r];
    float dtb = dtb_g[kd];

    float h[NS], P[NS];
#pragma unroll
    for (int n = 0; n < NS; n++) { h[n] = 0.f; P[n] = 1.f; }

    const float* xdbase = xdbl + ((size_t)bk * LL + c * CS) * 38;
    const float* xb = xxT + (size_t)b * LL * DI;

    for (int s = 0; s < CS; s++) {
        const float* xd = xdbase + s * 38;
        int hw = hw_of_l(k, c * CS + s);
        float u = xb[(size_t)hw * DI + d];
        float dt = dtb;
#pragma unroll
        for (int r = 0; r < RK; r++) dt = fmaf(xd[r], dtw[r], dt);
        dt = (dt > 20.f) ? dt : __logf(1.f + __expf(dt));
        float du = dt * u;
#pragma unroll
        for (int n = 0; n < NS; n++) {
            float a = __expf(dt * A[n]);
            h[n] = fmaf(a, h[n], du * xd[6 + n]);
            P[n] *= a;
        }
    }
    size_t base = ((size_t)blk * DI + d) * NS;
#pragma unroll
    for (int n = 0; n < NS; n++) { Pst[base + n] = P[n]; Hloc[base + n] = h[n]; }
}

// middle compose: 2 chains/thread (float2), depth-4 explicit prefetch
__global__ void scan_mid(const float* __restrict__ Pst, float* __restrict__ Hloc) {
    int gid = blockIdx.x * 256 + threadIdx.x;     // bk*1536 + j  (j = float2 idx)
    int bk = gid / 1536;
    int j = gid % 1536;
    const float2* Pp = (const float2*)(Pst + (size_t)bk * NC * (DI * NS)) + j;
    float2* Hp = (float2*)(Hloc + (size_t)bk * NC * (DI * NS)) + j;
    const int S = (DI * NS) / 2;     // stride between chunks in float2

    float2 h = make_float2(0.f, 0.f);
    float2 P[4], L[4];
#pragma unroll
    for (int q = 0; q < 4; q++) { P[q] = Pp[(size_t)q * S]; L[q] = Hp[(size_t)q * S]; }
    for (int c = 0; c < NC; c += 4) {
        float2 Pn[4], Ln[4];
        if (c + 4 < NC) {
#pragma unroll
            for (int q = 0; q < 4; q++) {
                Pn[q] = Pp[(size_t)(c + 4 + q) * S];
                Ln[q] = Hp[(size_t)(c + 4 + q) * S];
            }
        }
#pragma unroll
        for (int q = 0; q < 4; q++) {
            Hp[(size_t)(c + q) * S] = h;
            h.x = fmaf(P[q].x, h.x, L[q].x);
            h.y = fmaf(P[q].y, h.y, L[q].y);
        }
#pragma unroll
        for (int q = 0; q < 4; q++) { P[q] = Pn[q]; L[q] = Ln[q]; }
    }
}

__global__ void scan_p3(const float* __restrict__ xxT, const float* __restrict__ xdbl,
                        const float* __restrict__ dtw_g, const float* __restrict__ dtb_g,
                        const float* __restrict__ Alog, const float* __restrict__ Ds,
                        const float* __restrict__ Hin, float* __restrict__ ysm) {
    int blk = blockIdx.x;
    int bk = blk / NC, c = blk % NC;
    int k = bk & 3, b = bk >> 2;
    int d = threadIdx.x;
    int kd = k * DI + d;

    float A[NS];
#pragma unroll
    for (int n = 0; n < NS; n++) A[n] = -__expf(Alog[(size_t)kd * NS + n]);
    float dtw[RK];
#pragma unroll
    for (int r = 0; r < RK; r++) dtw[r] = dtw_g[(size_t)kd * RK + r];
    float dtb = dtb_g[kd];
    float Dp = Ds[kd];

    float h[NS];
    size_t hbase = ((size_t)blk * DI + d) * NS;
#pragma unroll
    for (int n = 0; n < NS; n++) h[n] = Hin[hbase + n];

    const float* xdbase = xdbl + ((size_t)bk * LL + c * CS) * 38;
    const float* xb = xxT + (size_t)b * LL * DI;
    float* yk = ysm + (size_t)bk * LL * DI;

    for (int s = 0; s < CS; s++) {
        const float* xd = xdbase + s * 38;
        int hw = hw_of_l(k, c * CS + s);
        float u = xb[(size_t)hw * DI + d];
        float dt = dtb;
#pragma unroll
        for (int r = 0; r < RK; r++) dt = fmaf(xd[r], dtw[r], dt);
        dt = (dt > 20.f) ? dt : __logf(1.f + __expf(dt));
        float du = dt * u;
        float y = 0.f;
#pragma unroll
        for (int n = 0; n < NS; n++) {
            float a = __expf(dt * A[n]);
            h[n] = fmaf(a, h[n], du * xd[6 + n]);
            y = fmaf(h[n], xd[22 + n], y);
        }
        yk[(size_t)hw * DI + d] = fmaf(Dp, u, y);   // write at spatial position
    }
}

// ---- cross-merge: now fully sequential reads (ysm is hw-ordered) ----------
#define MT 16
__global__ void merge_k(const float* __restrict__ ysm, float* __restrict__ ym,
                        float* __restrict__ stats) {
    __shared__ float tile[MT][DI + 1];
    __shared__ float sh1[3], sh2[3];
    int b = blockIdx.y;
    int hw0 = blockIdx.x * MT;
    int d = threadIdx.x;
    const float* yb = ysm + (size_t)b * KK * LL * DI;

    float s1 = 0.f, s2 = 0.f;
#pragma unroll
    for (int hwi = 0; hwi < MT; hwi++) {
        int hw = hw0 + hwi;
        float v = yb[((size_t)0 * LL + hw) * DI + d]
                + yb[((size_t)1 * LL + hw) * DI + d]
                + yb[((size_t)2 * LL + hw) * DI + d]
                + yb[((size_t)3 * LL + hw) * DI + d];
        tile[hwi][d] = v;
        s1 += v; s2 = fmaf(v, v, s2);
    }
#pragma unroll
    for (int off = 32; off > 0; off >>= 1) {
        s1 += __shfl_down(s1, off);
        s2 += __shfl_down(s2, off);
    }
    int lane = threadIdx.x & 63, wid = threadIdx.x >> 6;
    if (lane == 0) { sh1[wid] = s1; sh2[wid] = s2; }
    __syncthreads();
    if (threadIdx.x == 0) {
        atomicAdd(&stats[b * 2],     sh1[0] + sh1[1] + sh1[2]);
        atomicAdd(&stats[b * 2 + 1], sh2[0] + sh2[1] + sh2[2]);
    }
#pragma unroll
    for (int rep = 0; rep < MT; rep++) {
        int j = rep * DI + threadIdx.x;
        int d2 = j >> 4;
        int hwi = j & (MT - 1);
        ym[((size_t)b * DI + d2) * LL + hw0 + hwi] = tile[hwi][d2];
    }
}

// normalize + gamma/beta + multiply silu(z)
__global__ void yz_k(const float* __restrict__ ym, const float* __restrict__ zs,
                     const float* __restrict__ g, const float* __restrict__ be,
                     const float* __restrict__ stats, float* __restrict__ yz) {
    int idx = blockIdx.x * 256 + threadIdx.x;
    int c = (idx >> 10) % DI;
    int b = idx / (LL * DI);
    const float Ninv = 1.f / (float)(DI * LL);
    float mu = stats[b * 2] * Ninv;
    float var = stats[b * 2 + 1] * Ninv - mu * mu;
    float rstd = rsqrtf(var + 1e-6f);
    float v = (ym[idx] - mu) * rstd * g[c] + be[c];
    yz[idx] = v * zs[idx];
}

// out projection: 4 outputs per thread
__global__ void out_k(const float* __restrict__ yz, const float* __restrict__ wo,
                      float* __restrict__ out) {
    int bi = blockIdx.x;                 // 4 lblk * 24 og * 4 b
    int t = threadIdx.x;
    int lb = bi & 3;
    int og = (bi >> 2) % 24;
    int b = bi / 96;
    int l = lb * 256 + t;
    const float* yb = yz + (size_t)b * DI * LL + l;
    float acc[4];
#pragma unroll
    for (int g = 0; g < 4; g++) acc[g] = 0.f;
    for (int c = 0; c < DI; c++) {
        float yv = yb[(size_t)c * LL];
#pragma unroll
        for (int g = 0; g < 4; g++)
            acc[g] = fmaf(yv, wo[(size_t)(og * 4 + g) * DI + c], acc[g]);
    }
#pragma unroll
    for (int g = 0; g < 4; g++)
        out[((size_t)b * DM + og * 4 + g) * LL + l] = acc[g];
}

extern "C" void kernel_launch(void* const* d_in, const int* in_sizes, int n_in,
                              void* d_out, int out_size, void* d_ws, size_t ws_size,
                              hipStream_t stream) {
    const float* x    = (const float*)d_in[0];
    const float* ipw  = (const float*)d_in[1];
    const float* cw   = (const float*)d_in[2];
    const float* cb   = (const float*)d_in[3];
    const float* xpw  = (const float*)d_in[4];
    const float* dtw  = (const float*)d_in[5];
    const float* dtb  = (const float*)d_in[6];
    const float* Alog = (const float*)d_in[7];
    const float* Ds   = (const float*)d_in[8];
    const float* gng  = (const float*)d_in[9];
    const float* gnb  = (const float*)d_in[10];
    const float* opw  = (const float*)d_in[11];
    float* out = (float*)d_out;

    float* ws = (float*)d_ws;
    const size_t o_xx   = 0;                                       // (→ ym)
    const size_t o_zs   = o_xx   + (size_t)Bsz * DI * LL;
    const size_t o_xxT  = o_zs   + (size_t)Bsz * DI * LL;
    const size_t o_xdbl = o_xxT  + (size_t)Bsz * LL * DI;
    const size_t o_P    = o_xdbl + (size_t)Bsz * KK * LL * 38;     // (→ yz)
    const size_t o_H    = o_P    + (size_t)Bsz * KK * NC * DI * NS;
    const size_t o_ysm  = o_H    + (size_t)Bsz * KK * NC * DI * NS;
    const size_t o_st   = o_ysm  + (size_t)Bsz * KK * LL * DI;

    float* xx    = ws + o_xx;
    float* zs    = ws + o_zs;
    float* xxT   = ws + o_xxT;
    float* xdbl  = ws + o_xdbl;
    float* Pst   = ws + o_P;
    float* Hst   = ws + o_H;
    float* ysm   = ws + o_ysm;
    float* stats = ws + o_st;
    float* ym = xx;    // xx dead after convT
    float* yz = Pst;   // Pst dead after scan_mid

    hipLaunchKernelGGL(in_proj_k, dim3(768), dim3(256), 0, stream, x, ipw, xx, zs, stats);
    hipLaunchKernelGGL(convT_k, dim3(384), dim3(256), 0, stream, xx, cw, cb, xxT);
    hipLaunchKernelGGL(xdbl_k, dim3(256), dim3(512), 0, stream, xxT, xpw, xdbl);
    hipLaunchKernelGGL(scan_p1, dim3(Bsz * KK * NC), dim3(192), 0, stream,
                       xxT, xdbl, dtw, dtb, Alog, Pst, Hst);
    hipLaunchKernelGGL(scan_mid, dim3(96), dim3(256), 0, stream, Pst, Hst);
    hipLaunchKernelGGL(scan_p3, dim3(Bsz * KK * NC), dim3(192), 0, stream,
                       xxT, xdbl, dtw, dtb, Alog, Ds, Hst, ysm);
    hipLaunchKernelGGL(merge_k, dim3(LL / MT, Bsz), dim3(192), 0, stream, ysm, ym, stats);
    hipLaunchKernelGGL(yz_k, dim3(3072), dim3(256), 0, stream, ym, zs, gng, gnb, stats, yz);
    hipLaunchKernelGGL(out_k, dim3(384), dim3(256), 0, stream, yz, opw, out);
}